// Round 1
// baseline (1999.574 us; speedup 1.0000x reference)
//
#include <hip/hip_runtime.h>
#include <math.h>

#define BB 32
#define TT 32
#define D_INX 128
#define NSLOT 512
#define MLEN 64
#define NREAD 4
#define NHEAD 5          // 4 read + 1 write
#define CDIM 256
#define KCTRL 384        // D_IN + NUM_READ*M_LEN
#define IDIM 478
#define RHL 70

// One workgroup per batch. 1024 threads = 16 waves. Whole T=32 scan inside
// the kernel; only __syncthreads() barriers (no cross-WG communication).
// Mem[b] (512x64 fp32 = 128KB) lives in d_ws; weights stream from L2 each step.
__global__ __launch_bounds__(1024)
void ntm_kernel(const float* __restrict__ x,
                const float* __restrict__ Wc,
                const float* __restrict__ bc,
                const float* __restrict__ Hk,
                const float* __restrict__ hb,
                float* __restrict__ out,
                float* __restrict__ mem_ws)
{
    const int b    = blockIdx.x;
    const int tid  = threadIdx.x;
    const int lane = tid & 63;
    const int wave = tid >> 6;     // 0..15

    float* Mem = mem_ws + (size_t)b * NSLOT * MLEN;

    __shared__ float s_ctrl[KCTRL];
    __shared__ float s_h[CDIM];
    __shared__ float s_instr[IDIM + 2];
    __shared__ float s_red[4 * 256];
    __shared__ float s_red2[2 * 512];
    __shared__ float s_wbuf[NHEAD][NSLOT];    // sim -> wg scratch
    __shared__ float s_wprev[NHEAD][NSLOT];   // persistent addresses (0..3 read, 4 write)
    __shared__ float s_Mn[NSLOT];             // persistent row norms
    __shared__ float s_r[NREAD * MLEN];       // persistent read vectors
    __shared__ float s_rpart[16][NREAD][MLEN];
    __shared__ float s_bred5[16][NHEAD];
    __shared__ float s_mx5[NHEAD];
    __shared__ float s_sum5[NHEAD];
    __shared__ float s_beta[NHEAD], s_g[NHEAD], s_tp[NHEAD], s_kn[NHEAD];
    __shared__ float s_sh[NHEAD][3];
    __shared__ float s_e[MLEN], s_a[MLEN];

    // ---- init persistent state (ws is poisoned 0xAA every launch) ----
    for (int i = tid; i < NHEAD * NSLOT; i += 1024) (&s_wprev[0][0])[i] = 0.f;
    for (int i = tid; i < NSLOT; i += 1024) s_Mn[i] = 0.f;
    for (int i = tid; i < NREAD * MLEN; i += 1024) s_r[i] = 0.f;
    for (int i = tid; i < NSLOT * MLEN; i += 1024) Mem[i] = 0.f;
    __syncthreads();

    for (int t = 0; t < TT; ++t) {
        // ---- stage ctrl_in = [x_t, r] ----
        for (int i = tid; i < D_INX; i += 1024)
            s_ctrl[i] = x[((size_t)b * TT + t) * D_INX + i];
        for (int i = tid; i < NREAD * MLEN; i += 1024)
            s_ctrl[D_INX + i] = s_r[i];
        __syncthreads();

        // ---- h = tanh(ctrl @ Wc + bc): j = tid&255, 4-way K split ----
        {
            int j = tid & 255, kb = tid >> 8;
            float acc = 0.f;
            int i0 = kb * 96;
            for (int i = i0; i < i0 + 96; ++i)
                acc += s_ctrl[i] * Wc[(size_t)i * CDIM + j];
            s_red[kb * 256 + j] = acc;
        }
        __syncthreads();
        if (tid < CDIM) {
            float v = bc[tid] + s_red[tid] + s_red[256 + tid] + s_red[512 + tid] + s_red[768 + tid];
            s_h[tid] = tanhf(v);
        }
        __syncthreads();

        if (t == TT - 1) {           // output is h at the last step; skip the rest
            if (tid < CDIM) out[b * CDIM + tid] = s_h[tid];
            break;
        }

        // ---- instr = h @ Hk + hb: j = tid&511 (<478), 2-way K split ----
        {
            int j = tid & 511, kb = tid >> 9;
            if (j < IDIM) {
                float acc = 0.f;
                int i0 = kb * 128;
                for (int i = i0; i < i0 + 128; ++i)
                    acc += s_h[i] * Hk[(size_t)i * IDIM + j];
                s_red2[kb * 512 + j] = acc;
            }
        }
        __syncthreads();
        if (tid < IDIM) s_instr[tid] = hb[tid] + s_red2[tid] + s_red2[512 + tid];
        __syncthreads();

        // ---- parse heads ----
        if (tid < NHEAD) {
            int base = tid * RHL;                  // write head lands at 280
            s_beta[tid] = expf(s_instr[base + MLEN]);
            s_g[tid] = 1.f / (1.f + expf(-s_instr[base + MLEN + 1]));
            float v0 = s_instr[base + 66], v1 = s_instr[base + 67], v2 = s_instr[base + 68];
            float mx = fmaxf(v0, fmaxf(v1, v2));
            float e0 = expf(v0 - mx), e1 = expf(v1 - mx), e2 = expf(v2 - mx);
            float inv = 1.f / (e0 + e1 + e2);
            s_sh[tid][0] = e0 * inv; s_sh[tid][1] = e1 * inv; s_sh[tid][2] = e2 * inv;
            float tv = s_instr[base + 69];
            s_tp[tid] = fmaxf(tv, 0.f) + log1pf(expf(-fabsf(tv))) + 1.f;   // softplus + 1
        }
        if (tid >= 64 && tid < 128)       s_e[tid - 64]  = s_instr[280 + RHL + (tid - 64)];
        else if (tid >= 128 && tid < 192) s_a[tid - 128] = s_instr[280 + RHL + MLEN + (tid - 128)];
        if (wave < NHEAD) {               // kn = ||k_h||
            float v = s_instr[wave * RHL + lane];
            float sq = v * v;
            for (int off = 32; off > 0; off >>= 1) sq += __shfl_down(sq, off);
            if (lane == 0) s_kn[wave] = sqrtf(sq);
        }
        __syncthreads();

        // ---- sim pass: n = tid>>1, m half = (tid&1)*32; Mem row read once for all 5 heads
        {
            int n = tid >> 1, m0 = (tid & 1) * 32;
            const float4* row4 = (const float4*)(Mem + n * MLEN + m0);
            float mv[32];
            float4* mv4 = (float4*)mv;
#pragma unroll
            for (int i = 0; i < 8; ++i) mv4[i] = row4[i];
#pragma unroll
            for (int hh = 0; hh < NHEAD; ++hh) {
                const float* kk = &s_instr[hh * RHL + m0];
                float d = 0.f;
#pragma unroll
                for (int j = 0; j < 32; ++j) d += mv[j] * kk[j];
                d += __shfl_xor(d, 1);
                if ((tid & 1) == 0) {
                    float sim = d / (s_kn[hh] * s_Mn[n] + 1e-8f);
                    s_wbuf[hh][n] = s_beta[hh] * sim;
                }
            }
        }
        __syncthreads();

        // ---- addressing, all 5 heads fused: softmax(beta*sim) -> gate -> shift -> sharpen -> renorm
        {
            bool act = tid < NSLOT;
            float u[NHEAD], evv[NHEAD], wt[NHEAD];
#pragma unroll
            for (int hh = 0; hh < NHEAD; ++hh) u[hh] = act ? s_wbuf[hh][tid] : -INFINITY;
#pragma unroll
            for (int hh = 0; hh < NHEAD; ++hh) {
                float m = u[hh];
                for (int off = 32; off > 0; off >>= 1) m = fmaxf(m, __shfl_xor(m, off));
                if (lane == 0) s_bred5[wave][hh] = m;
            }
            __syncthreads();
            if (tid < NHEAD) {
                float m = -INFINITY;
                for (int w = 0; w < 16; ++w) m = fmaxf(m, s_bred5[w][tid]);
                s_mx5[tid] = m;
            }
            __syncthreads();
#pragma unroll
            for (int hh = 0; hh < NHEAD; ++hh) {
                evv[hh] = act ? expf(u[hh] - s_mx5[hh]) : 0.f;
                float s = evv[hh];
                for (int off = 32; off > 0; off >>= 1) s += __shfl_xor(s, off);
                if (lane == 0) s_bred5[wave][hh] = s;
            }
            __syncthreads();
            if (tid < NHEAD) {
                float s = 0.f;
                for (int w = 0; w < 16; ++w) s += s_bred5[w][tid];
                s_sum5[tid] = s;
            }
            __syncthreads();
            if (act) {
#pragma unroll
                for (int hh = 0; hh < NHEAD; ++hh) {
                    float wc = evv[hh] / s_sum5[hh];
                    float g = s_g[hh];
                    s_wbuf[hh][tid] = g * wc + (1.f - g) * s_wprev[hh][tid];
                }
            }
            __syncthreads();
#pragma unroll
            for (int hh = 0; hh < NHEAD; ++hh) {
                float w = 0.f;
                if (act) {
                    float wm = s_wbuf[hh][(tid + 1) & (NSLOT - 1)];
                    float w0 = s_wbuf[hh][tid];
                    float wp = s_wbuf[hh][(tid - 1) & (NSLOT - 1)];
                    float wsh = s_sh[hh][0] * wm + s_sh[hh][1] * w0 + s_sh[hh][2] * wp;
                    w = powf(wsh, s_tp[hh]);
                }
                wt[hh] = w;
                float s = w;
                for (int off = 32; off > 0; off >>= 1) s += __shfl_xor(s, off);
                if (lane == 0) s_bred5[wave][hh] = s;
            }
            __syncthreads();
            if (tid < NHEAD) {
                float s = 0.f;
                for (int w = 0; w < 16; ++w) s += s_bred5[w][tid];
                s_sum5[tid] = s + 1e-8f;
            }
            __syncthreads();
            if (act) {
#pragma unroll
                for (int hh = 0; hh < NHEAD; ++hh) s_wprev[hh][tid] = wt[hh] / s_sum5[hh];
            }
            __syncthreads();
        }

        // ---- erase/add update + fused row-norm for next step ----
        {
            int n = tid >> 1, m0 = (tid & 1) * 32;
            float* row = Mem + n * MLEN + m0;
            float wv = s_wprev[4][n];
            float mv[32];
            float4* mv4 = (float4*)mv;
            const float4* row4 = (const float4*)row;
#pragma unroll
            for (int i = 0; i < 8; ++i) mv4[i] = row4[i];
            float nsq = 0.f;
#pragma unroll
            for (int j = 0; j < 32; ++j) {
                float nv = mv[j] * (1.f - wv * s_e[m0 + j]) + wv * s_a[m0 + j];
                mv[j] = nv;
                nsq += nv * nv;
            }
#pragma unroll
            for (int i = 0; i < 8; ++i) ((float4*)row)[i] = mv4[i];
            nsq += __shfl_xor(nsq, 1);
            if ((tid & 1) == 0) s_Mn[n] = sqrtf(nsq);
        }
        __syncthreads();

        // ---- read pass: r[h] = sum_n w[h][n] * Mem[n,:], Mem read once (16 wave-chunks)
        {
            int n0 = wave * 32;
            float a0 = 0.f, a1 = 0.f, a2 = 0.f, a3 = 0.f;
            for (int n = n0; n < n0 + 32; ++n) {
                float mvv = Mem[n * MLEN + lane];
                a0 += s_wprev[0][n] * mvv;
                a1 += s_wprev[1][n] * mvv;
                a2 += s_wprev[2][n] * mvv;
                a3 += s_wprev[3][n] * mvv;
            }
            s_rpart[wave][0][lane] = a0;
            s_rpart[wave][1][lane] = a1;
            s_rpart[wave][2][lane] = a2;
            s_rpart[wave][3][lane] = a3;
        }
        __syncthreads();
        if (tid < NREAD * MLEN) {
            int hh = tid >> 6, m = tid & 63;
            float s = 0.f;
            for (int w = 0; w < 16; ++w) s += s_rpart[w][hh][m];
            s_r[tid] = s;
        }
        __syncthreads();
    }
}

extern "C" void kernel_launch(void* const* d_in, const int* in_sizes, int n_in,
                              void* d_out, int out_size, void* d_ws, size_t ws_size,
                              hipStream_t stream) {
    const float* x  = (const float*)d_in[0];
    const float* Wc = (const float*)d_in[1];
    const float* bc = (const float*)d_in[2];
    const float* Hk = (const float*)d_in[3];
    const float* hb = (const float*)d_in[4];
    float* out = (float*)d_out;
    float* mem = (float*)d_ws;   // needs 32*512*64*4 = 4 MB
    hipLaunchKernelGGL(ntm_kernel, dim3(BB), dim3(1024), 0, stream,
                       x, Wc, bc, Hk, hb, out, mem);
}